// Round 12
// baseline (236.308 us; speedup 1.0000x reference)
//
#include <hip/hip_runtime.h>
#include <hip/hip_bf16.h>

#define NNODES 20000
#define NEDGES 160000
#define BQ     64
#define FTEXT  300
#define KPAD1  320          // FTEXT padded to multiple of 32
#define HIDDIM 1024
#define OUTDIM 1664
#define EB     (NEDGES / 256)       // 625 edge-blocks (exact)
#define SPLITK 13
#define KLEN   (OUTDIM / SPLITK)    // 128 (exact)

typedef __attribute__((ext_vector_type(8))) short short8;
typedef __attribute__((ext_vector_type(4))) float floatx4;

__device__ inline unsigned short f2bf(float f) {
    union { float f; unsigned int u; } v; v.f = f;
    unsigned int r = v.u + 0x7FFF + ((v.u >> 16) & 1);   // RNE
    return (unsigned short)(r >> 16);
}
__device__ inline float bf2f(unsigned short h) {
    union { unsigned int u; float f; } v; v.u = ((unsigned int)h) << 16;
    return v.f;
}

// async 16B global -> LDS (linear dest: wave-uniform base + lane*16)
__device__ inline void gload16(const unsigned short* g, unsigned short* l) {
    __builtin_amdgcn_global_load_lds(
        (const __attribute__((address_space(1))) unsigned int*)g,
        (__attribute__((address_space(3))) unsigned int*)l, 16, 0, 0);
}

// ============ K1: degcnt (blocks < EB)  ||  all conversions (rest) ============
// W1 emitted PHASE-TILED: 16 phases x [s(10)][lq(4)][col(64)][j(8)]
#define W1N  (HIDDIM * KPAD1)
#define N1F4 (HIDDIM * OUTDIM / 4)
#define N2F4 (BQ * OUTDIM / 4)
#define N3F4 (NNODES * FTEXT / 4)
__global__ __launch_bounds__(256) void prep_kernel(
        const int* __restrict__ dst, const float* __restrict__ w,
        float* __restrict__ deg, int* __restrict__ cnt,
        const float* __restrict__ W1, unsigned short* __restrict__ W1ch,
        const float* __restrict__ W2, unsigned short* __restrict__ W2b,
        const float* __restrict__ img, unsigned short* __restrict__ imgb,
        const float* __restrict__ nf, unsigned short* __restrict__ nfb) {
    if (blockIdx.x < EB) {
        int e = blockIdx.x * 256 + threadIdx.x;
        int d = dst[e];
        atomicAdd(&deg[d], w[e]);
        atomicAdd(&cnt[d], 1);
        return;
    }
    int i = (blockIdx.x - EB) * 256 + threadIdx.x;
    if (i < W1N) {
        int p   = i / 20480;        // 20480 ushorts per phase block
        int ww  = i - p * 20480;
        int s   = ww >> 11;
        int lq  = (ww >> 9) & 3;
        int col = (ww >> 3) & 63;
        int j   = ww & 7;
        int n = p * 64 + col;
        int k = s * 32 + lq * 8 + j;
        float v = (k < FTEXT) ? W1[(long)k * HIDDIM + n] : 0.f;
        W1ch[i] = f2bf(v);
        return;
    }
    i -= W1N;
    const float* in; unsigned short* outp; int j;
    if (i < N1F4)                    { in = W2;  outp = W2b;  j = i; }
    else if (i < N1F4 + N2F4)        { in = img; outp = imgb; j = i - N1F4; }
    else if (i < N1F4 + N2F4 + N3F4) { in = nf;  outp = nfb;  j = i - N1F4 - N2F4; }
    else return;
    float4 v = ((const float4*)in)[j];
    ushort4 o;
    o.x = f2bf(v.x); o.y = f2bf(v.y); o.z = f2bf(v.z); o.w = f2bf(v.w);
    ((ushort4*)outp)[j] = o;
}

// ============ K2: CSR scan (single block) ============
__global__ __launch_bounds__(1024) void scan_kernel(const int* __restrict__ cnt,
                                                    int* __restrict__ row_start, int N) {
    __shared__ int partial[1024];
    const int CH = 20;
    int t = threadIdx.x;
    int begin = t * CH;
    int nloc = N - begin; if (nloc > CH) nloc = CH; if (nloc < 0) nloc = 0;
    int vals[CH];
    int s = 0;
    if (nloc == CH) {
        #pragma unroll
        for (int i = 0; i < CH / 4; i++) {
            int4 v = ((const int4*)(cnt + begin))[i];
            vals[i*4+0] = v.x; vals[i*4+1] = v.y; vals[i*4+2] = v.z; vals[i*4+3] = v.w;
            s += v.x + v.y + v.z + v.w;
        }
    } else {
        for (int i = 0; i < nloc; i++) { vals[i] = cnt[begin + i]; s += vals[i]; }
    }
    partial[t] = s;
    __syncthreads();
    for (int off = 1; off < 1024; off <<= 1) {
        int v = (t >= off) ? partial[t - off] : 0;
        __syncthreads();
        partial[t] += v;
        __syncthreads();
    }
    int run = (t == 0) ? 0 : partial[t - 1];
    for (int i = 0; i < nloc; i++) { row_start[begin + i] = run; run += vals[i]; }
    if (t == 1023) row_start[N] = partial[1023];
}

// ============ K3: fill (blocks < EB)  ||  Ztf13 partial GEMM (208 blocks) ======
__global__ __launch_bounds__(256) void fillgemm_kernel(
        const int* __restrict__ dst, const int* __restrict__ src,
        const float* __restrict__ w, const float* __restrict__ deg,
        const int* __restrict__ row_start, int* __restrict__ cursor,
        int* __restrict__ src_s, float* __restrict__ wnrm_s,
        const unsigned short* __restrict__ imgb, const unsigned short* __restrict__ W2b,
        float* __restrict__ Ztf13) {
    __shared__ unsigned short As[128][40];
    __shared__ unsigned short Bs[64][40];
    if (blockIdx.x < EB) {
        int e = blockIdx.x * 256 + threadIdx.x;
        int d = dst[e], s = src[e];
        float dd = deg[d], ds = deg[s];
        float nv = (ds > 0.f ? rsqrtf(ds) : 0.f) * w[e] * (dd > 0.f ? rsqrtf(dd) : 0.f);
        int pos = row_start[d] + atomicAdd(&cursor[d], 1);
        src_s[pos] = s;
        wnrm_s[pos] = nv;
        return;
    }
    int bb = blockIdx.x - EB;
    int n0 = (bb & 15) * 64;
    int z  = bb >> 4;
    int kbeg = z * KLEN;
    int t = threadIdx.x;
    int wave = t >> 6, lane = t & 63;
    int lm = lane & 15, lq = lane >> 4;
    floatx4 acc[2][4] = {};
    for (int k0 = kbeg; k0 < kbeg + KLEN; k0 += 32) {
        #pragma unroll
        for (int p2 = 0; p2 < 2; p2++) {
            int idx = p2 * 256 + t;
            int r = idx >> 2, c8 = (idx & 3) * 8;
            uint4 v = make_uint4(0, 0, 0, 0);
            if (r < BQ) v = *(const uint4*)(imgb + (long)r * OUTDIM + k0 + c8);
            *(uint4*)&As[r][c8] = v;
        }
        {
            int r = t >> 2, c8 = (t & 3) * 8;
            uint4 v = *(const uint4*)(W2b + (long)(n0 + r) * OUTDIM + k0 + c8);
            *(uint4*)&Bs[r][c8] = v;
        }
        __syncthreads();
        short8 a[2], b[4];
        #pragma unroll
        for (int rt = 0; rt < 2; rt++)
            a[rt] = *(const short8*)&As[wave * 32 + rt * 16 + lm][lq * 8];
        #pragma unroll
        for (int ct = 0; ct < 4; ct++)
            b[ct] = *(const short8*)&Bs[ct * 16 + lm][lq * 8];
        #pragma unroll
        for (int rt = 0; rt < 2; rt++)
            #pragma unroll
            for (int ct = 0; ct < 4; ct++)
                acc[rt][ct] = __builtin_amdgcn_mfma_f32_16x16x32_bf16(
                    a[rt], b[ct], acc[rt][ct], 0, 0, 0);
        __syncthreads();
    }
    #pragma unroll
    for (int rt = 0; rt < 2; rt++)
        #pragma unroll
        for (int r = 0; r < 4; r++) {
            int gm = wave * 32 + rt * 16 + lq * 4 + r;
            if (gm >= BQ) continue;
            #pragma unroll
            for (int ct = 0; ct < 4; ct++)
                Ztf13[(long)z * BQ * HIDDIM + (long)gm * HIDDIM + n0 + ct * 16 + lm]
                    = acc[rt][ct][r];
        }
}

// ============ K4: aggNF (blocks < 5000)  ||  Zt reduce  ||  cvec ============
__global__ __launch_bounds__(256) void aggzt_kernel(
        const unsigned short* __restrict__ nfb, const int* __restrict__ row_start,
        const int* __restrict__ src_s, const float* __restrict__ wnrm_s,
        unsigned short* __restrict__ out,
        const float* __restrict__ Ztf13, unsigned short* __restrict__ Zt,
        const float* __restrict__ img, const float* __restrict__ b2,
        float* __restrict__ cvec) {
    __shared__ float red[256];
    if (blockIdx.x < NNODES / 4) {
        int wave = threadIdx.x >> 6, lane = threadIdx.x & 63;
        int d = blockIdx.x * 4 + wave;
        int s0 = row_start[d], s1 = row_start[d + 1];
        float4 acc  = make_float4(0.f, 0.f, 0.f, 0.f);
        float4 acc2 = make_float4(0.f, 0.f, 0.f, 0.f);
        for (int base = s0; base < s1; base += 64) {
            int m = s1 - base; if (m > 64) m = 64;
            int   src_l = (lane < m) ? src_s[base + lane]  : 0;
            float w_l   = (lane < m) ? wnrm_s[base + lane] : 0.f;
            int sj = __shfl(src_l, 0);
            float wj = __shfl(w_l, 0);
            const ushort4* row = (const ushort4*)(nfb + (long)sj * FTEXT);
            ushort4 hv  = row[lane];
            ushort4 hv2 = make_ushort4(0, 0, 0, 0);
            if (lane < 11) hv2 = row[64 + lane];
            for (int j = 0; j < m; j++) {
                ushort4 nv  = make_ushort4(0, 0, 0, 0);
                ushort4 nv2 = make_ushort4(0, 0, 0, 0);
                float wn = 0.f;
                if (j + 1 < m) {
                    int sn = __shfl(src_l, j + 1);
                    wn = __shfl(w_l, j + 1);
                    const ushort4* nrow = (const ushort4*)(nfb + (long)sn * FTEXT);
                    nv = nrow[lane];
                    if (lane < 11) nv2 = nrow[64 + lane];
                }
                acc.x  += bf2f(hv.x)  * wj; acc.y  += bf2f(hv.y)  * wj;
                acc.z  += bf2f(hv.z)  * wj; acc.w  += bf2f(hv.w)  * wj;
                acc2.x += bf2f(hv2.x) * wj; acc2.y += bf2f(hv2.y) * wj;
                acc2.z += bf2f(hv2.z) * wj; acc2.w += bf2f(hv2.w) * wj;
                hv = nv; hv2 = nv2; wj = wn;
            }
        }
        unsigned short* orow = out + (long)d * KPAD1;
        ushort4 o;
        o.x = f2bf(acc.x); o.y = f2bf(acc.y); o.z = f2bf(acc.z); o.w = f2bf(acc.w);
        ((ushort4*)orow)[lane] = o;
        if (lane < 16) {
            ushort4 o2 = make_ushort4(0, 0, 0, 0);
            if (lane < 11) {
                o2.x = f2bf(acc2.x); o2.y = f2bf(acc2.y);
                o2.z = f2bf(acc2.z); o2.w = f2bf(acc2.w);
            }
            ((ushort4*)orow)[64 + lane] = o2;
        }
        return;
    }
    int bb = blockIdx.x - NNODES / 4;
    if (bb < (BQ * HIDDIM) / 256) {
        int i = bb * 256 + threadIdx.x;
        float s = 0.f;
        #pragma unroll
        for (int z = 0; z < SPLITK; z++) s += Ztf13[(long)z * BQ * HIDDIM + i];
        Zt[i] = f2bf(s);
    } else {
        int b = bb - (BQ * HIDDIM) / 256;
        int l = threadIdx.x;
        float v = 0.f;
        for (int f = l; f < OUTDIM; f += 256) v += img[(long)b * OUTDIM + f] * b2[f];
        red[l] = v;
        __syncthreads();
        if (l < 64) {
            v = red[l] + red[l + 64] + red[l + 128] + red[l + 192];
            for (int off = 32; off > 0; off >>= 1) v += __shfl_down(v, off);
            if (l == 0) cvec[b] = v;
        }
    }
}

// ============ K5: FUSED x = leaky(aggNF@W1^T+b1); Y = x @ Zt^T ============
// R8-proven body VERBATIM, launched as TWO half-grid dispatches (boff = block
// offset).  Purpose: drop the rocprof top-5 visibility threshold from 46us to
// ~23us so the non-xy kernels' durations finally become measurable.  Costs one
// dispatch gap (~5us); body, LDS, counters per-block unchanged.
__global__ __launch_bounds__(256, 3) void xy_gemm(
        const unsigned short* __restrict__ aggNF, const unsigned short* __restrict__ W1ch,
        const float* __restrict__ b1, const unsigned short* __restrict__ Zt,
        float* __restrict__ Y, int boff) {
    __shared__ unsigned short Bsh[20480];    // 40 KB: [s(10)][lq(4)][col(64)][j(8)]
    __shared__ unsigned short xs[32][76];    // 4,864 B
    int t = threadIdx.x;
    int wn = t >> 6, lane = t & 63;          // wave wn: col-slice wn*16 (GEMM1+2)
    int lm = lane & 15, lq = lane >> 4;
    int m0 = (blockIdx.x + boff) * 32;

    short8 afr[2][10];
    #pragma unroll
    for (int rt = 0; rt < 2; rt++) {
        const unsigned short* ap = aggNF + (long)(m0 + rt * 16 + lm) * KPAD1 + lq * 8;
        #pragma unroll
        for (int kk = 0; kk < 10; kk++)
            afr[rt][kk] = *(const short8*)(ap + kk * 32);
    }
    {
        const unsigned short* src = W1ch + t * 8;
        #pragma unroll
        for (int r = 0; r < 10; r++)
            gload16(src + r * 2048, &Bsh[t * 8 + r * 2048]);
    }
    floatx4 yacc[2] = {};
    for (int p = 0; p < 16; p++) {
        __syncthreads();             // bar A: stage p drained; xs of p-1 consumed
        floatx4 acc[2] = {};
        #pragma unroll
        for (int s = 0; s < 10; s++) {
            short8 b = *(const short8*)&Bsh[s * 2048 + lq * 512 + (wn * 16 + lm) * 8];
            acc[0] = __builtin_amdgcn_mfma_f32_16x16x32_bf16(afr[0][s], b, acc[0], 0, 0, 0);
            acc[1] = __builtin_amdgcn_mfma_f32_16x16x32_bf16(afr[1][s], b, acc[1], 0, 0, 0);
        }
        {
            int col = wn * 16 + lm;
            float bv = b1[p * 64 + col];
            #pragma unroll
            for (int rt = 0; rt < 2; rt++)
                #pragma unroll
                for (int r = 0; r < 4; r++) {
                    float v = acc[rt][r] + bv;
                    v = v >= 0.f ? v : 0.2f * v;
                    xs[rt * 16 + lq * 4 + r][col] = f2bf(v);
                }
        }
        __syncthreads();             // bar B: xs complete + all B-reads done
        if (p + 1 < 16) {
            const unsigned short* src = W1ch + (long)(p + 1) * 20480 + t * 8;
            #pragma unroll
            for (int r = 0; r < 10; r++)
                gload16(src + r * 2048, &Bsh[t * 8 + r * 2048]);
        }
        #pragma unroll
        for (int kk = 0; kk < 2; kk++) {
            short8 b = *(const short8*)(Zt + (long)(wn * 16 + lm) * HIDDIM
                                            + p * 64 + kk * 32 + lq * 8);
            #pragma unroll
            for (int rt = 0; rt < 2; rt++) {
                short8 a = *(const short8*)&xs[rt * 16 + lm][kk * 32 + lq * 8];
                yacc[rt] = __builtin_amdgcn_mfma_f32_16x16x32_bf16(a, b, yacc[rt], 0, 0, 0);
            }
        }
    }
    #pragma unroll
    for (int rt = 0; rt < 2; rt++)
        #pragma unroll
        for (int r = 0; r < 4; r++)
            Y[(long)(m0 + rt * 16 + lq * 4 + r) * 64 + wn * 16 + lm] = yacc[rt][r];
}

// ============ K6: out[b,d] = sum_{e:dst=d} w*Y[src,b] + c[b] ============
__global__ __launch_bounds__(256) void outagg_kernel(const float* __restrict__ Y,
        const int* __restrict__ row_start, const int* __restrict__ src_s,
        const float* __restrict__ wnrm_s, const float* __restrict__ c,
        float* __restrict__ out, int N) {
    __shared__ float tile[4][68];
    int d0 = blockIdx.x * 4;
    int t = threadIdx.x;
    int wave = t >> 6, lane = t & 63;
    int d = d0 + wave;
    int s0 = row_start[d], s1 = row_start[d + 1];
    float acc = 0.f;
    for (int base = s0; base < s1; base += 64) {
        int m = s1 - base; if (m > 64) m = 64;
        int   src_l = (lane < m) ? src_s[base + lane]  : 0;
        float w_l   = (lane < m) ? wnrm_s[base + lane] : 0.f;
        int sj = __shfl(src_l, 0);
        float wj = __shfl(w_l, 0);
        float yv = Y[(long)sj * 64 + lane];
        for (int j = 0; j < m; j++) {
            float yn = 0.f, wn = 0.f;
            if (j + 1 < m) {
                int sn = __shfl(src_l, j + 1);
                wn = __shfl(w_l, j + 1);
                yn = Y[(long)sn * 64 + lane];
            }
            acc += wj * yv;
            yv = yn; wj = wn;
        }
    }
    tile[wave][lane] = acc + c[lane];
    __syncthreads();
    int b = t >> 2, j = t & 3;
    out[(long)b * N + d0 + j] = tile[j][b];
}

extern "C" void kernel_launch(void* const* d_in, const int* in_sizes, int n_in,
                              void* d_out, int out_size, void* d_ws, size_t ws_size,
                              hipStream_t stream) {
    const float* img_feat      = (const float*)d_in[0];
    const float* node_features = (const float*)d_in[1];
    const int*   edge_src      = (const int*)d_in[2];
    const int*   edge_dst      = (const int*)d_in[3];
    const float* edge_weight   = (const float*)d_in[4];
    const float* W1            = (const float*)d_in[5];
    const float* b1            = (const float*)d_in[6];
    const float* W2            = (const float*)d_in[7];
    const float* b2            = (const float*)d_in[8];
    float* out = (float*)d_out;

    const int N = NNODES;

    char* ws = (char*)d_ws;
    size_t off = 0;
    auto alloc = [&](size_t bytes) -> void* {
        void* p = ws + off;
        off = (off + bytes + 255) & ~(size_t)255;
        return p;
    };
    // ---- zero-initialized region (single small memset) ----
    float*          deg       = (float*)alloc((size_t)N * 4);
    int*            cnt       = (int*)alloc((size_t)N * 4);
    int*            cursor    = (int*)alloc((size_t)N * 4);
    size_t zero_bytes = off;
    // ---- rest (no zeroing needed) ----
    float*          Ztf13     = (float*)alloc((size_t)SPLITK * BQ * HIDDIM * 4);
    float*          Y         = (float*)alloc((size_t)N * BQ * 4);
    int*            row_start = (int*)alloc((size_t)(N + 1) * 4);
    int*            src_s     = (int*)alloc((size_t)NEDGES * 4);
    float*          wnrm_s    = (float*)alloc((size_t)NEDGES * 4);
    unsigned short* aggNF     = (unsigned short*)alloc((size_t)N * KPAD1 * 2);
    unsigned short* W1ch      = (unsigned short*)alloc((size_t)HIDDIM * KPAD1 * 2);
    unsigned short* W2b       = (unsigned short*)alloc((size_t)HIDDIM * OUTDIM * 2);
    unsigned short* imgb      = (unsigned short*)alloc((size_t)BQ * OUTDIM * 2);
    unsigned short* nfb       = (unsigned short*)alloc((size_t)N * FTEXT * 2);
    unsigned short* Zt        = (unsigned short*)alloc((size_t)BQ * HIDDIM * 2);
    float*          cvec      = (float*)alloc((size_t)BQ * 4);

    hipMemsetAsync(ws, 0, zero_bytes, stream);

    int cvb = (W1N + N1F4 + N2F4 + N3F4 + 255) / 256;
    prep_kernel<<<EB + cvb, 256, 0, stream>>>(
        edge_dst, edge_weight, deg, cnt,
        W1, W1ch, W2, W2b, img_feat, imgb, node_features, nfb);

    scan_kernel<<<1, 1024, 0, stream>>>(cnt, row_start, N);

    fillgemm_kernel<<<EB + 16 * SPLITK, 256, 0, stream>>>(
        edge_dst, edge_src, edge_weight, deg, row_start, cursor, src_s, wnrm_s,
        imgb, W2b, Ztf13);

    aggzt_kernel<<<NNODES / 4 + (BQ * HIDDIM) / 256 + BQ, 256, 0, stream>>>(
        nfb, row_start, src_s, wnrm_s, aggNF, Ztf13, Zt, img_feat, b2, cvec);

    // xy split into two half-grids: drops top-5 threshold to ~23us so the
    // non-xy kernels become visible in the profile (diagnostic, ~5us cost)
    xy_gemm<<<312, 256, 0, stream>>>(aggNF, W1ch, b1, Zt, Y, 0);
    xy_gemm<<<313, 256, 0, stream>>>(aggNF, W1ch, b1, Zt, Y, 312);

    outagg_kernel<<<N / 4, 256, 0, stream>>>(Y, row_start, src_s, wnrm_s, cvec, out, N);
}

// Round 13
// 213.374 us; speedup vs baseline: 1.1075x; 1.1075x over previous
//
#include <hip/hip_runtime.h>
#include <hip/hip_bf16.h>

#define NNODES 20000
#define NEDGES 160000
#define BQ     64
#define FTEXT  300
#define KPAD1  320          // FTEXT padded to multiple of 32
#define HIDDIM 1024
#define OUTDIM 1664
#define EB     (NEDGES / 256)       // 625 edge-blocks (exact)
#define SPLITK 13
#define KLEN   (OUTDIM / SPLITK)    // 128 (exact)

typedef __attribute__((ext_vector_type(8))) short short8;
typedef __attribute__((ext_vector_type(4))) float floatx4;

__device__ inline unsigned short f2bf(float f) {
    union { float f; unsigned int u; } v; v.f = f;
    unsigned int r = v.u + 0x7FFF + ((v.u >> 16) & 1);   // RNE
    return (unsigned short)(r >> 16);
}
__device__ inline float bf2f(unsigned short h) {
    union { unsigned int u; float f; } v; v.u = ((unsigned int)h) << 16;
    return v.f;
}

// async 16B global -> LDS (linear dest: wave-uniform base + lane*16)
__device__ inline void gload16(const unsigned short* g, unsigned short* l) {
    __builtin_amdgcn_global_load_lds(
        (const __attribute__((address_space(1))) unsigned int*)g,
        (__attribute__((address_space(3))) unsigned int*)l, 16, 0, 0);
}

// ============ K1: degcnt (blocks < EB)  ||  all conversions (rest) ============
// W1 emitted PHASE-TILED: 16 phases x [s(10)][lq(4)][col(64)][j(8)]
#define W1N  (HIDDIM * KPAD1)
#define N1F4 (HIDDIM * OUTDIM / 4)
#define N2F4 (BQ * OUTDIM / 4)
#define N3F4 (NNODES * FTEXT / 4)
__global__ __launch_bounds__(256) void prep_kernel(
        const int* __restrict__ dst, const float* __restrict__ w,
        float* __restrict__ deg, int* __restrict__ cnt,
        const float* __restrict__ W1, unsigned short* __restrict__ W1ch,
        const float* __restrict__ W2, unsigned short* __restrict__ W2b,
        const float* __restrict__ img, unsigned short* __restrict__ imgb,
        const float* __restrict__ nf, unsigned short* __restrict__ nfb) {
    if (blockIdx.x < EB) {
        int e = blockIdx.x * 256 + threadIdx.x;
        int d = dst[e];
        atomicAdd(&deg[d], w[e]);
        atomicAdd(&cnt[d], 1);
        return;
    }
    int i = (blockIdx.x - EB) * 256 + threadIdx.x;
    if (i < W1N) {
        int p   = i / 20480;        // 20480 ushorts per phase block
        int ww  = i - p * 20480;
        int s   = ww >> 11;
        int lq  = (ww >> 9) & 3;
        int col = (ww >> 3) & 63;
        int j   = ww & 7;
        int n = p * 64 + col;
        int k = s * 32 + lq * 8 + j;
        float v = (k < FTEXT) ? W1[(long)k * HIDDIM + n] : 0.f;
        W1ch[i] = f2bf(v);
        return;
    }
    i -= W1N;
    const float* in; unsigned short* outp; int j;
    if (i < N1F4)                    { in = W2;  outp = W2b;  j = i; }
    else if (i < N1F4 + N2F4)        { in = img; outp = imgb; j = i - N1F4; }
    else if (i < N1F4 + N2F4 + N3F4) { in = nf;  outp = nfb;  j = i - N1F4 - N2F4; }
    else return;
    float4 v = ((const float4*)in)[j];
    ushort4 o;
    o.x = f2bf(v.x); o.y = f2bf(v.y); o.z = f2bf(v.z); o.w = f2bf(v.w);
    ((ushort4*)outp)[j] = o;
}

// ============ K2: CSR scan (single block) ============
__global__ __launch_bounds__(1024) void scan_kernel(const int* __restrict__ cnt,
                                                    int* __restrict__ row_start, int N) {
    __shared__ int partial[1024];
    const int CH = 20;
    int t = threadIdx.x;
    int begin = t * CH;
    int nloc = N - begin; if (nloc > CH) nloc = CH; if (nloc < 0) nloc = 0;
    int vals[CH];
    int s = 0;
    if (nloc == CH) {
        #pragma unroll
        for (int i = 0; i < CH / 4; i++) {
            int4 v = ((const int4*)(cnt + begin))[i];
            vals[i*4+0] = v.x; vals[i*4+1] = v.y; vals[i*4+2] = v.z; vals[i*4+3] = v.w;
            s += v.x + v.y + v.z + v.w;
        }
    } else {
        for (int i = 0; i < nloc; i++) { vals[i] = cnt[begin + i]; s += vals[i]; }
    }
    partial[t] = s;
    __syncthreads();
    for (int off = 1; off < 1024; off <<= 1) {
        int v = (t >= off) ? partial[t - off] : 0;
        __syncthreads();
        partial[t] += v;
        __syncthreads();
    }
    int run = (t == 0) ? 0 : partial[t - 1];
    for (int i = 0; i < nloc; i++) { row_start[begin + i] = run; run += vals[i]; }
    if (t == 1023) row_start[N] = partial[1023];
}

// ============ K3: fill (blocks < EB)  ||  Ztf13 partial GEMM (208 blocks) ======
__global__ __launch_bounds__(256) void fillgemm_kernel(
        const int* __restrict__ dst, const int* __restrict__ src,
        const float* __restrict__ w, const float* __restrict__ deg,
        const int* __restrict__ row_start, int* __restrict__ cursor,
        int* __restrict__ src_s, float* __restrict__ wnrm_s,
        const unsigned short* __restrict__ imgb, const unsigned short* __restrict__ W2b,
        float* __restrict__ Ztf13) {
    __shared__ unsigned short As[128][40];
    __shared__ unsigned short Bs[64][40];
    if (blockIdx.x < EB) {
        int e = blockIdx.x * 256 + threadIdx.x;
        int d = dst[e], s = src[e];
        float dd = deg[d], ds = deg[s];
        float nv = (ds > 0.f ? rsqrtf(ds) : 0.f) * w[e] * (dd > 0.f ? rsqrtf(dd) : 0.f);
        int pos = row_start[d] + atomicAdd(&cursor[d], 1);
        src_s[pos] = s;
        wnrm_s[pos] = nv;
        return;
    }
    int bb = blockIdx.x - EB;
    int n0 = (bb & 15) * 64;
    int z  = bb >> 4;
    int kbeg = z * KLEN;
    int t = threadIdx.x;
    int wave = t >> 6, lane = t & 63;
    int lm = lane & 15, lq = lane >> 4;
    floatx4 acc[2][4] = {};
    for (int k0 = kbeg; k0 < kbeg + KLEN; k0 += 32) {
        #pragma unroll
        for (int p2 = 0; p2 < 2; p2++) {
            int idx = p2 * 256 + t;
            int r = idx >> 2, c8 = (idx & 3) * 8;
            uint4 v = make_uint4(0, 0, 0, 0);
            if (r < BQ) v = *(const uint4*)(imgb + (long)r * OUTDIM + k0 + c8);
            *(uint4*)&As[r][c8] = v;
        }
        {
            int r = t >> 2, c8 = (t & 3) * 8;
            uint4 v = *(const uint4*)(W2b + (long)(n0 + r) * OUTDIM + k0 + c8);
            *(uint4*)&Bs[r][c8] = v;
        }
        __syncthreads();
        short8 a[2], b[4];
        #pragma unroll
        for (int rt = 0; rt < 2; rt++)
            a[rt] = *(const short8*)&As[wave * 32 + rt * 16 + lm][lq * 8];
        #pragma unroll
        for (int ct = 0; ct < 4; ct++)
            b[ct] = *(const short8*)&Bs[ct * 16 + lm][lq * 8];
        #pragma unroll
        for (int rt = 0; rt < 2; rt++)
            #pragma unroll
            for (int ct = 0; ct < 4; ct++)
                acc[rt][ct] = __builtin_amdgcn_mfma_f32_16x16x32_bf16(
                    a[rt], b[ct], acc[rt][ct], 0, 0, 0);
        __syncthreads();
    }
    #pragma unroll
    for (int rt = 0; rt < 2; rt++)
        #pragma unroll
        for (int r = 0; r < 4; r++) {
            int gm = wave * 32 + rt * 16 + lq * 4 + r;
            if (gm >= BQ) continue;
            #pragma unroll
            for (int ct = 0; ct < 4; ct++)
                Ztf13[(long)z * BQ * HIDDIM + (long)gm * HIDDIM + n0 + ct * 16 + lm]
                    = acc[rt][ct][r];
        }
}

// ============ K4: aggNF (blocks < 5000)  ||  Zt reduce  ||  cvec ============
__global__ __launch_bounds__(256) void aggzt_kernel(
        const unsigned short* __restrict__ nfb, const int* __restrict__ row_start,
        const int* __restrict__ src_s, const float* __restrict__ wnrm_s,
        unsigned short* __restrict__ out,
        const float* __restrict__ Ztf13, unsigned short* __restrict__ Zt,
        const float* __restrict__ img, const float* __restrict__ b2,
        float* __restrict__ cvec) {
    __shared__ float red[256];
    if (blockIdx.x < NNODES / 4) {
        int wave = threadIdx.x >> 6, lane = threadIdx.x & 63;
        int d = blockIdx.x * 4 + wave;
        int s0 = row_start[d], s1 = row_start[d + 1];
        float4 acc  = make_float4(0.f, 0.f, 0.f, 0.f);
        float4 acc2 = make_float4(0.f, 0.f, 0.f, 0.f);
        for (int base = s0; base < s1; base += 64) {
            int m = s1 - base; if (m > 64) m = 64;
            int   src_l = (lane < m) ? src_s[base + lane]  : 0;
            float w_l   = (lane < m) ? wnrm_s[base + lane] : 0.f;
            int sj = __shfl(src_l, 0);
            float wj = __shfl(w_l, 0);
            const ushort4* row = (const ushort4*)(nfb + (long)sj * FTEXT);
            ushort4 hv  = row[lane];
            ushort4 hv2 = make_ushort4(0, 0, 0, 0);
            if (lane < 11) hv2 = row[64 + lane];
            for (int j = 0; j < m; j++) {
                ushort4 nv  = make_ushort4(0, 0, 0, 0);
                ushort4 nv2 = make_ushort4(0, 0, 0, 0);
                float wn = 0.f;
                if (j + 1 < m) {
                    int sn = __shfl(src_l, j + 1);
                    wn = __shfl(w_l, j + 1);
                    const ushort4* nrow = (const ushort4*)(nfb + (long)sn * FTEXT);
                    nv = nrow[lane];
                    if (lane < 11) nv2 = nrow[64 + lane];
                }
                acc.x  += bf2f(hv.x)  * wj; acc.y  += bf2f(hv.y)  * wj;
                acc.z  += bf2f(hv.z)  * wj; acc.w  += bf2f(hv.w)  * wj;
                acc2.x += bf2f(hv2.x) * wj; acc2.y += bf2f(hv2.y) * wj;
                acc2.z += bf2f(hv2.z) * wj; acc2.w += bf2f(hv2.w) * wj;
                hv = nv; hv2 = nv2; wj = wn;
            }
        }
        unsigned short* orow = out + (long)d * KPAD1;
        ushort4 o;
        o.x = f2bf(acc.x); o.y = f2bf(acc.y); o.z = f2bf(acc.z); o.w = f2bf(acc.w);
        ((ushort4*)orow)[lane] = o;
        if (lane < 16) {
            ushort4 o2 = make_ushort4(0, 0, 0, 0);
            if (lane < 11) {
                o2.x = f2bf(acc2.x); o2.y = f2bf(acc2.y);
                o2.z = f2bf(acc2.z); o2.w = f2bf(acc2.w);
            }
            ((ushort4*)orow)[64 + lane] = o2;
        }
        return;
    }
    int bb = blockIdx.x - NNODES / 4;
    if (bb < (BQ * HIDDIM) / 256) {
        int i = bb * 256 + threadIdx.x;
        float s = 0.f;
        #pragma unroll
        for (int z = 0; z < SPLITK; z++) s += Ztf13[(long)z * BQ * HIDDIM + i];
        Zt[i] = f2bf(s);
    } else {
        int b = bb - (BQ * HIDDIM) / 256;
        int l = threadIdx.x;
        float v = 0.f;
        for (int f = l; f < OUTDIM; f += 256) v += img[(long)b * OUTDIM + f] * b2[f];
        red[l] = v;
        __syncthreads();
        if (l < 64) {
            v = red[l] + red[l + 64] + red[l + 128] + red[l + 192];
            for (int off = 32; off > 0; off >>= 1) v += __shfl_down(v, off);
            if (l == 0) cvec[b] = v;
        }
    }
}

// ============ K5: FUSED x = leaky(aggNF@W1^T+b1); Y = x @ Zt^T ============
// R8 structure (625 blocks, 4 col-partitioned waves, 3 blocks/CU) with ONE
// change: the GEMM2 Zt operands (2x short8) and the b1 bias are now loaded
// RIGHT AFTER bar A (before the GEMM1 MFMA block) instead of after bar B.
// Their ~300-600cy L2 latency lands under GEMM1 and is drained by bar B's
// existing vmcnt(0) -- previously it was fully exposed every phase (16x).
__global__ __launch_bounds__(256, 3) void xy_gemm(
        const unsigned short* __restrict__ aggNF, const unsigned short* __restrict__ W1ch,
        const float* __restrict__ b1, const unsigned short* __restrict__ Zt,
        float* __restrict__ Y, int M) {
    __shared__ unsigned short Bsh[20480];    // 40 KB: [s(10)][lq(4)][col(64)][j(8)]
    __shared__ unsigned short xs[32][76];    // 4,864 B
    int t = threadIdx.x;
    int wn = t >> 6, lane = t & 63;          // wave wn: col-slice wn*16 (GEMM1+2)
    int lm = lane & 15, lq = lane >> 4;
    int m0 = blockIdx.x * 32;

    short8 afr[2][10];
    #pragma unroll
    for (int rt = 0; rt < 2; rt++) {
        const unsigned short* ap = aggNF + (long)(m0 + rt * 16 + lm) * KPAD1 + lq * 8;
        #pragma unroll
        for (int kk = 0; kk < 10; kk++)
            afr[rt][kk] = *(const short8*)(ap + kk * 32);
    }
    {
        const unsigned short* src = W1ch + t * 8;
        #pragma unroll
        for (int r = 0; r < 10; r++)
            gload16(src + r * 2048, &Bsh[t * 8 + r * 2048]);
    }
    const unsigned short* zrow = Zt + (long)(wn * 16 + lm) * HIDDIM + lq * 8;
    const float* brow = b1 + wn * 16 + lm;
    floatx4 yacc[2] = {};
    for (int p = 0; p < 16; p++) {
        __syncthreads();             // bar A: stage p drained; xs of p-1 consumed
        // EARLY-ISSUE: GEMM2 operands + bias for THIS phase (land under GEMM1,
        // drained by bar B -- zero exposed latency at their use sites)
        short8 z0 = *(const short8*)(zrow + p * 64);
        short8 z1 = *(const short8*)(zrow + p * 64 + 32);
        float bv = brow[p * 64];
        floatx4 acc[2] = {};
        #pragma unroll
        for (int s = 0; s < 10; s++) {
            short8 b = *(const short8*)&Bsh[s * 2048 + lq * 512 + (wn * 16 + lm) * 8];
            acc[0] = __builtin_amdgcn_mfma_f32_16x16x32_bf16(afr[0][s], b, acc[0], 0, 0, 0);
            acc[1] = __builtin_amdgcn_mfma_f32_16x16x32_bf16(afr[1][s], b, acc[1], 0, 0, 0);
        }
        {
            int col = wn * 16 + lm;
            #pragma unroll
            for (int rt = 0; rt < 2; rt++)
                #pragma unroll
                for (int r = 0; r < 4; r++) {
                    float v = acc[rt][r] + bv;
                    v = v >= 0.f ? v : 0.2f * v;
                    xs[rt * 16 + lq * 4 + r][col] = f2bf(v);
                }
        }
        __syncthreads();             // bar B: xs complete + all B-reads done
        if (p + 1 < 16) {
            const unsigned short* src = W1ch + (long)(p + 1) * 20480 + t * 8;
            #pragma unroll
            for (int r = 0; r < 10; r++)
                gload16(src + r * 2048, &Bsh[t * 8 + r * 2048]);
        }
        #pragma unroll
        for (int rt = 0; rt < 2; rt++) {
            short8 a0 = *(const short8*)&xs[rt * 16 + lm][lq * 8];
            yacc[rt] = __builtin_amdgcn_mfma_f32_16x16x32_bf16(a0, z0, yacc[rt], 0, 0, 0);
            short8 a1 = *(const short8*)&xs[rt * 16 + lm][32 + lq * 8];
            yacc[rt] = __builtin_amdgcn_mfma_f32_16x16x32_bf16(a1, z1, yacc[rt], 0, 0, 0);
        }
    }
    #pragma unroll
    for (int rt = 0; rt < 2; rt++)
        #pragma unroll
        for (int r = 0; r < 4; r++)
            Y[(long)(m0 + rt * 16 + lq * 4 + r) * 64 + wn * 16 + lm] = yacc[rt][r];
}

// ============ K6: out[b,d] = sum_{e:dst=d} w*Y[src,b] + c[b] ============
__global__ __launch_bounds__(256) void outagg_kernel(const float* __restrict__ Y,
        const int* __restrict__ row_start, const int* __restrict__ src_s,
        const float* __restrict__ wnrm_s, const float* __restrict__ c,
        float* __restrict__ out, int N) {
    __shared__ float tile[4][68];
    int d0 = blockIdx.x * 4;
    int t = threadIdx.x;
    int wave = t >> 6, lane = t & 63;
    int d = d0 + wave;
    int s0 = row_start[d], s1 = row_start[d + 1];
    float acc = 0.f;
    for (int base = s0; base < s1; base += 64) {
        int m = s1 - base; if (m > 64) m = 64;
        int   src_l = (lane < m) ? src_s[base + lane]  : 0;
        float w_l   = (lane < m) ? wnrm_s[base + lane] : 0.f;
        int sj = __shfl(src_l, 0);
        float wj = __shfl(w_l, 0);
        float yv = Y[(long)sj * 64 + lane];
        for (int j = 0; j < m; j++) {
            float yn = 0.f, wn = 0.f;
            if (j + 1 < m) {
                int sn = __shfl(src_l, j + 1);
                wn = __shfl(w_l, j + 1);
                yn = Y[(long)sn * 64 + lane];
            }
            acc += wj * yv;
            yv = yn; wj = wn;
        }
    }
    tile[wave][lane] = acc + c[lane];
    __syncthreads();
    int b = t >> 2, j = t & 3;
    out[(long)b * N + d0 + j] = tile[j][b];
}

extern "C" void kernel_launch(void* const* d_in, const int* in_sizes, int n_in,
                              void* d_out, int out_size, void* d_ws, size_t ws_size,
                              hipStream_t stream) {
    const float* img_feat      = (const float*)d_in[0];
    const float* node_features = (const float*)d_in[1];
    const int*   edge_src      = (const int*)d_in[2];
    const int*   edge_dst      = (const int*)d_in[3];
    const float* edge_weight   = (const float*)d_in[4];
    const float* W1            = (const float*)d_in[5];
    const float* b1            = (const float*)d_in[6];
    const float* W2            = (const float*)d_in[7];
    const float* b2            = (const float*)d_in[8];
    float* out = (float*)d_out;

    const int N = NNODES;

    char* ws = (char*)d_ws;
    size_t off = 0;
    auto alloc = [&](size_t bytes) -> void* {
        void* p = ws + off;
        off = (off + bytes + 255) & ~(size_t)255;
        return p;
    };
    // ---- zero-initialized region (single small memset) ----
    float*          deg       = (float*)alloc((size_t)N * 4);
    int*            cnt       = (int*)alloc((size_t)N * 4);
    int*            cursor    = (int*)alloc((size_t)N * 4);
    size_t zero_bytes = off;
    // ---- rest (no zeroing needed) ----
    float*          Ztf13     = (float*)alloc((size_t)SPLITK * BQ * HIDDIM * 4);
    float*          Y         = (float*)alloc((size_t)N * BQ * 4);
    int*            row_start = (int*)alloc((size_t)(N + 1) * 4);
    int*            src_s     = (int*)alloc((size_t)NEDGES * 4);
    float*          wnrm_s    = (float*)alloc((size_t)NEDGES * 4);
    unsigned short* aggNF     = (unsigned short*)alloc((size_t)N * KPAD1 * 2);
    unsigned short* W1ch      = (unsigned short*)alloc((size_t)HIDDIM * KPAD1 * 2);
    unsigned short* W2b       = (unsigned short*)alloc((size_t)HIDDIM * OUTDIM * 2);
    unsigned short* imgb      = (unsigned short*)alloc((size_t)BQ * OUTDIM * 2);
    unsigned short* nfb       = (unsigned short*)alloc((size_t)N * FTEXT * 2);
    unsigned short* Zt        = (unsigned short*)alloc((size_t)BQ * HIDDIM * 2);
    float*          cvec      = (float*)alloc((size_t)BQ * 4);

    hipMemsetAsync(ws, 0, zero_bytes, stream);

    int cvb = (W1N + N1F4 + N2F4 + N3F4 + 255) / 256;
    prep_kernel<<<EB + cvb, 256, 0, stream>>>(
        edge_dst, edge_weight, deg, cnt,
        W1, W1ch, W2, W2b, img_feat, imgb, node_features, nfb);

    scan_kernel<<<1, 1024, 0, stream>>>(cnt, row_start, N);

    fillgemm_kernel<<<EB + 16 * SPLITK, 256, 0, stream>>>(
        edge_dst, edge_src, edge_weight, deg, row_start, cursor, src_s, wnrm_s,
        imgb, W2b, Ztf13);

    aggzt_kernel<<<NNODES / 4 + (BQ * HIDDIM) / 256 + BQ, 256, 0, stream>>>(
        nfb, row_start, src_s, wnrm_s, aggNF, Ztf13, Zt, img_feat, b2, cvec);

    xy_gemm<<<NNODES / 32, 256, 0, stream>>>(aggNF, W1ch, b1, Zt, Y, N);

    outagg_kernel<<<N / 4, 256, 0, stream>>>(Y, row_start, src_s, wnrm_s, cvec, out, N);
}